// Round 8
// baseline (333.771 us; speedup 1.0000x reference)
//
#include <hip/hip_runtime.h>
#include <hip/hip_bf16.h>

// Transformer block fwd: B=2, T=2048, C=1024, H=16, D=64.
// out = concat(x_out fp32 [2,2048,1024], k fp32 [2,16,2048,64], v fp32 [2,16,2048,64])

#define T_SEQ 2048
#define C_DIM 1024
#define HEADS 16
#define HD    64

typedef __attribute__((ext_vector_type(8))) short s16x8;   // 8 x bf16 (4 VGPR) — MFMA A/B frag
typedef __attribute__((ext_vector_type(4))) short s16x4;
typedef __attribute__((ext_vector_type(4))) float f32x4;   // MFMA C/D frag

__device__ __forceinline__ short f2bf(float f) {
    union { __hip_bfloat16 h; short s; } u;
    u.h = __float2bfloat16(f);
    return u.s;
}

// async global->LDS, 16B per lane. LDS dest = wave-uniform base + lane*16 (linear).
__device__ __forceinline__ void gload16(const void* g, void* l) {
    __builtin_amdgcn_global_load_lds(
        (const __attribute__((address_space(1))) void*)g,
        (__attribute__((address_space(3))) void*)l, 16, 0, 0);
}
#define VMCNT0 asm volatile("s_waitcnt vmcnt(0)" ::: "memory")
#define BARRAW asm volatile("s_barrier" ::: "memory")
#define PRIO1  __builtin_amdgcn_s_setprio(1)
#define PRIO0  __builtin_amdgcn_s_setprio(0)

template<int N> __device__ __forceinline__ void vmcnt_n() {
    asm volatile("s_waitcnt vmcnt(%0)" :: "n"(N) : "memory");
}

// ---------------- weight transpose + cast: W[K][N] fp32 -> Wt[N][K] bf16 ----------------
__global__ __launch_bounds__(256) void transpose_cast_kernel(
    const float* __restrict__ W, short* __restrict__ Wt, int K, int N) {
    __shared__ float t[32][33];
    int n0 = blockIdx.x * 32, k0 = blockIdx.y * 32;
    int tx = threadIdx.x, ty = threadIdx.y;
#pragma unroll
    for (int i = 0; i < 4; i++) t[ty + 8 * i][tx] = W[(k0 + ty + 8 * i) * N + n0 + tx];
    __syncthreads();
#pragma unroll
    for (int i = 0; i < 4; i++) Wt[(n0 + ty + 8 * i) * K + k0 + tx] = f2bf(t[tx][ty + 8 * i]);
}

// ---------------- LayerNorm: one block per row of [4096][1024], bf16 out ----------------
__global__ __launch_bounds__(256) void ln_kernel(
    const float* __restrict__ x, const float* __restrict__ w, const float* __restrict__ b,
    short* __restrict__ out) {
    int row = blockIdx.x, tid = threadIdx.x;
    float4 v = ((const float4*)(x + row * C_DIM))[tid];
    float s  = v.x + v.y + v.z + v.w;
    float sq = v.x * v.x + v.y * v.y + v.z * v.z + v.w * v.w;
#pragma unroll
    for (int off = 32; off > 0; off >>= 1) {
        s  += __shfl_down(s, off, 64);
        sq += __shfl_down(sq, off, 64);
    }
    __shared__ float rs[4], rq[4];
    int wv = tid >> 6, ln = tid & 63;
    if (ln == 0) { rs[wv] = s; rq[wv] = sq; }
    __syncthreads();
    s = rs[0] + rs[1] + rs[2] + rs[3];
    sq = rq[0] + rq[1] + rq[2] + rq[3];
    float mean = s * (1.f / C_DIM);
    float rstd = rsqrtf(sq * (1.f / C_DIM) - mean * mean + 1e-5f);
    float4 wv4 = ((const float4*)w)[tid];
    float4 bv4 = ((const float4*)b)[tid];
    s16x4 o;
    o[0] = f2bf((v.x - mean) * rstd * wv4.x + bv4.x);
    o[1] = f2bf((v.y - mean) * rstd * wv4.y + bv4.y);
    o[2] = f2bf((v.z - mean) * rstd * wv4.z + bv4.z);
    o[3] = f2bf((v.w - mean) * rstd * wv4.w + bv4.w);
    *(s16x4*)(out + row * C_DIM + tid * 4) = o;
}

// ---- residual + LN2 + PROJ-output init: xout = x+y+b_proj (fp32), h2 = LN(x+y) bf16 ----
__global__ __launch_bounds__(256) void resln_kernel(
    const float* __restrict__ x, const float* __restrict__ y,
    const float* __restrict__ w, const float* __restrict__ b,
    const float* __restrict__ bproj,
    short* __restrict__ out, float* __restrict__ xout) {
    int row = blockIdx.x, tid = threadIdx.x;
    float4 vx = ((const float4*)(x + row * C_DIM))[tid];
    float4 vy = ((const float4*)(y + row * C_DIM))[tid];
    float4 v;
    v.x = vx.x + vy.x; v.y = vx.y + vy.y; v.z = vx.z + vy.z; v.w = vx.w + vy.w;
    float4 bp = ((const float4*)bproj)[tid];
    float4 xo;
    xo.x = v.x + bp.x; xo.y = v.y + bp.y; xo.z = v.z + bp.z; xo.w = v.w + bp.w;
    ((float4*)(xout + row * C_DIM))[tid] = xo;   // PROJ GEMM atomically adds onto this
    float s  = v.x + v.y + v.z + v.w;
    float sq = v.x * v.x + v.y * v.y + v.z * v.z + v.w * v.w;
#pragma unroll
    for (int off = 32; off > 0; off >>= 1) {
        s  += __shfl_down(s, off, 64);
        sq += __shfl_down(sq, off, 64);
    }
    __shared__ float rs[4], rq[4];
    int wv = tid >> 6, ln = tid & 63;
    if (ln == 0) { rs[wv] = s; rq[wv] = sq; }
    __syncthreads();
    s = rs[0] + rs[1] + rs[2] + rs[3];
    sq = rq[0] + rq[1] + rq[2] + rq[3];
    float mean = s * (1.f / C_DIM);
    float rstd = rsqrtf(sq * (1.f / C_DIM) - mean * mean + 1e-5f);
    float4 wv4 = ((const float4*)w)[tid];
    float4 bv4 = ((const float4*)b)[tid];
    s16x4 o;
    o[0] = f2bf((v.x - mean) * rstd * wv4.x + bv4.x);
    o[1] = f2bf((v.y - mean) * rstd * wv4.y + bv4.y);
    o[2] = f2bf((v.z - mean) * rstd * wv4.z + bv4.z);
    o[3] = f2bf((v.w - mean) * rstd * wv4.w + bv4.w);
    *(s16x4*)(out + row * C_DIM + tid * 4) = o;
}

// ---------------- 256x256 GEMM, BK=32, TRIPLE-buffered LDS, 1 barrier + 1 counted vmcnt/K-tile --
// C = A[M,Kc](bf16, stride LDA) @ Bt[N,Kc]^T + epilogue. 8 waves (2Mx4N), wave tile 128x64.
// LDS 96 KB = 3 x (A 256x32 + B 256x32) bf16. Per K-tile t: {stage(t+2) into buf[(t+2)%3];
// compute(t) from buf[t%3]: 12 ds_read_b128 + 32 MFMA, no internal barriers; vmcnt(4) [= t+2's
// 4 loads outstanding => t+1 fully landed]; s_barrier}. 2-K-tile staging lookahead, never drains.
// Ledger: buf[(t+2)%3] last read by tile t-1, finished at t's entry barrier (= t-1's exit) before
// stage(t+2) issues; tile t staged at t-2, guaranteed by t-1's vmcnt(4)+barrier.
// Swizzle (64-B rows): src chunk (lane&3)^((lane>>2)&3); read col-XOR ((row&3)<<4). Residual
// 4-way bank conflict on frag reads (m136: 1.58x) — accepted.
// MODE 0: fused QKV; MODE 1: FC+GELU; MODE 2: split-K partial, atomicAdd into of0 (no bias).
template<int MODE>
__global__ __launch_bounds__(512, 1) void gemm3(
    const short* __restrict__ A, const short* __restrict__ Bt,
    int K, int LDA, int N,
    const float* __restrict__ b0, const float* __restrict__ b1, const float* __restrict__ b2,
    short* __restrict__ os0, short* __restrict__ os1, short* __restrict__ os2,
    float* __restrict__ of0) {
    constexpr int BM = 256, BN = 256;
    constexpr int MFR = 8, NFR = 4;                 // wave tile 128x64, 16x16 frags

    __shared__ short As[3][BM * 32];
    __shared__ short Bs[3][BN * 32];

    const int tid = threadIdx.x;
    const int wv = tid >> 6, lane = tid & 63, g = lane >> 4, r4 = lane & 15;
    const int wm = wv >> 2, wn = wv & 3;
    const int l16 = lane >> 2;                      // row 0..15 within 16-row DMA group
    const int sc4 = (lane & 3) ^ (l16 & 3);         // pre-swizzled 16B chunk (4 per 64-B row)
    const int xorb = (r4 & 3) << 4;                 // read-side col XOR (row&3 == r4&3)

    const int nwg = gridDim.x * gridDim.y;
    const int bid = blockIdx.y * gridDim.x + blockIdx.x;
    const int swz = (bid & 7) * (nwg >> 3) + (bid >> 3);   // bijective, nwg % 8 == 0
    const int m0 = (swz % gridDim.x) * BM;
    const int yy = swz / gridDim.x;
    int n0, kch;
    if constexpr (MODE == 2) {
        kch = yy >> 2;            // split-K chunk (4 chunks of K)
        n0 = (yy & 3) * BN;       // N/BN = 4
    } else {
        kch = 0;
        n0 = yy * BN;
    }
    const size_t kbase = (size_t)kch * K;
    // per-lane global source: row (R0 + l16), chunk sc4 (16B units)
    const size_t aoff = (size_t)m0 * LDA + kbase + (size_t)l16 * LDA + sc4 * 8;
    const size_t boff = (size_t)n0 * LDA + kbase + (size_t)l16 * LDA + sc4 * 8;

    const f32x4 zero4 = {0.f, 0.f, 0.f, 0.f};
    f32x4 acc[MFR][NFR];
#pragma unroll
    for (int i = 0; i < MFR; i++)
#pragma unroll
        for (int j = 0; j < NFR; j++) acc[i][j] = zero4;

    // stage K-tile t1 into buffer bb: per wave 2 gloads for A + 2 for B (16 rows each)
    auto stage = [&](int bb, int t1) {
#pragma unroll
        for (int j = 0; j < 2; j++) {
            int R0 = (j * 8 + wv) * 16;
            gload16(A  + aoff + (size_t)R0 * LDA + (size_t)t1 * 32, &As[bb][R0 * 32]);
            gload16(Bt + boff + (size_t)R0 * LDA + (size_t)t1 * 32, &Bs[bb][R0 * 32]);
        }
    };

    // prologue: stage tiles 0 and 1; wait for tile 0 (tile 1's 4 loads stay in flight)
    stage(0, 0);
    stage(1, 1);
    vmcnt_n<4>();
    BARRAW;

    const int NT = K >> 5;
    int cur = 0;
    for (int t = 0; t < NT; ++t) {
        const bool st = (t + 2 < NT);
        int sbuf = cur + 2; if (sbuf >= 3) sbuf -= 3;
        if (st) stage(sbuf, t + 2);

        const char* Ac = (const char*)&As[cur][0];
        const char* Bc = (const char*)&Bs[cur][0];
        // B frags for this wave's 64-col strip (4 reads), then progressive A rows + MFMA
        s16x8 bF[NFR];
#pragma unroll
        for (int nf = 0; nf < NFR; nf++) {
            int row = wn * 64 + nf * 16 + r4;
            bF[nf] = *(const s16x8*)(Bc + (row * 64 + ((g * 16) ^ xorb)));
        }
        PRIO1;
#pragma unroll
        for (int mf = 0; mf < MFR; mf++) {
            int row = wm * 128 + mf * 16 + r4;
            s16x8 aF = *(const s16x8*)(Ac + (row * 64 + ((g * 16) ^ xorb)));
#pragma unroll
            for (int nf = 0; nf < NFR; nf++)
                acc[mf][nf] = __builtin_amdgcn_mfma_f32_16x16x32_bf16(
                    aF, bF[nf], acc[mf][nf], 0, 0, 0);
        }
        PRIO0;
        if (st) vmcnt_n<4>(); else vmcnt_n<0>();   // counted: t+1 landed, t+2 in flight
        BARRAW;
        cur = (cur + 1 == 3) ? 0 : cur + 1;
    }

    // epilogue: D layout col = lane&15, row = 4*(lane>>4)+r  [verified m89/m91]
#pragma unroll
    for (int mf = 0; mf < MFR; mf++) {
#pragma unroll
        for (int nf = 0; nf < NFR; nf++) {
            int n = n0 + wn * 64 + nf * 16 + r4;
#pragma unroll
            for (int r = 0; r < 4; r++) {
                int m = m0 + wm * 128 + mf * 16 + 4 * g + r;
                float val = acc[mf][nf][r];
                if constexpr (MODE == 0) {
                    int sel = n >> 10, nn = n & 1023;
                    const float* bp = (sel == 0) ? b0 : ((sel == 1) ? b1 : b2);
                    val += bp[nn];
                    int bb2 = m >> 11, tt = m & 2047, h = nn >> 6, d = nn & 63;
                    int qi = ((bb2 * HEADS + h) * T_SEQ + tt) * HD + d;
                    if (sel == 0) {
                        os0[qi] = f2bf(val);
                    } else if (sel == 1) {
                        os1[qi] = f2bf(val);
                        of0[qi] = val;                   // kout
                    } else {
                        of0[4194304 + qi] = val;        // vout
                        os2[((bb2 * HEADS + h) * HD + d) * T_SEQ + tt] = f2bf(val);
                    }
                } else if constexpr (MODE == 1) {
                    val += b0[n];
                    val = 0.5f * val * (1.f + erff(val * 0.70710678118f));  // exact GELU
                    os0[m * N + n] = f2bf(val);
                } else {
                    atomicAdd(&of0[(size_t)m * N + n], val);  // onto x+y+b_proj init
                }
            }
        }
    }
}

// ---------------- causal flash attention (swapped QK^T, lane-local softmax) ----------------
__global__ __launch_bounds__(256) void attn_kernel(
    const short* __restrict__ qb, const short* __restrict__ kb,
    const short* __restrict__ vtb, float* __restrict__ y) {
    __shared__ short Ks[2][64 * 64];
    __shared__ short Vs[2][64 * 64];
    __shared__ short Ps[4][16 * 64];
    int qtr = (gridDim.x - 1) - blockIdx.x;
    int bh = blockIdx.y;
    int tid = threadIdx.x, w = tid >> 6, lane = tid & 63, g = lane >> 4, r4 = lane & 15;
    int qbase = qtr * 64;
    int lr = lane >> 3, lc = lane & 7, sc = lc ^ lr;

    const short* Qp = qb + ((size_t)bh * T_SEQ + qbase + w * 16 + r4) * HD;
    s16x8 qf0 = *(const s16x8*)&Qp[g * 8];
    s16x8 qf1 = *(const s16x8*)&Qp[32 + g * 8];

    const f32x4 zero4 = {0.f, 0.f, 0.f, 0.f};
    f32x4 yacc[4];
#pragma unroll
    for (int ni = 0; ni < 4; ni++) yacc[ni] = zero4;
    float mrun = -1e30f, lrun = 0.f;

#pragma unroll
    for (int j = 0; j < 2; j++) {
        int rw = (w * 2 + j) * 8 + lr;
        gload16(kb  + ((size_t)bh * T_SEQ + rw) * HD + sc * 8, &Ks[0][(w * 2 + j) * 512]);
        gload16(vtb + ((size_t)bh * HD + rw) * T_SEQ + sc * 8, &Vs[0][(w * 2 + j) * 512]);
    }
    VMCNT0;
    __syncthreads();

    int nst = qtr + 1;
    for (int st = 0; st < nst; ++st) {
        int cur = st & 1;
        int s0 = st * 64;
        if (st + 1 < nst) {
#pragma unroll
            for (int j = 0; j < 2; j++) {
                int rw = (w * 2 + j) * 8 + lr;
                gload16(kb  + ((size_t)bh * T_SEQ + s0 + 64 + rw) * HD + sc * 8,
                        &Ks[cur ^ 1][(w * 2 + j) * 512]);
                gload16(vtb + ((size_t)bh * HD + rw) * T_SEQ + s0 + 64 + sc * 8,
                        &Vs[cur ^ 1][(w * 2 + j) * 512]);
            }
        }
        f32x4 sacc[4];
#pragma unroll
        for (int sb = 0; sb < 4; sb++) sacc[sb] = zero4;
#pragma unroll
        for (int kk = 0; kk < 2; kk++) {
            s16x8 qf = (kk == 0) ? qf0 : qf1;
#pragma unroll
            for (int sb = 0; sb < 4; sb++) {
                int srow = sb * 16 + r4;
                s16x8 kf = *(const s16x8*)((const char*)&Ks[cur][0] +
                            ((srow * 128 + kk * 64 + g * 16) ^ ((r4 & 7) << 4)));
                sacc[sb] = __builtin_amdgcn_mfma_f32_16x16x32_bf16(kf, qf, sacc[sb], 0, 0, 0);
            }
        }
        bool diag = (st == qtr);
        float p[4][4];
        float mx = -1e30f;
#pragma unroll
        for (int sb = 0; sb < 4; sb++)
#pragma unroll
            for (int r = 0; r < 4; r++) {
                float v = sacc[sb][r] * 0.125f;
                if (diag) {
                    int kv = s0 + sb * 16 + 4 * g + r;
                    int qg = qbase + w * 16 + r4;
                    if (kv > qg) v = -1e30f;
                }
                p[sb][r] = v;
                mx = fmaxf(mx, v);
            }
        mx = fmaxf(mx, __shfl_xor(mx, 16, 64));
        mx = fmaxf(mx, __shfl_xor(mx, 32, 64));
        float mnew = fmaxf(mrun, mx);
        float alpha = __expf(mrun - mnew);
        float rsum = 0.f;
#pragma unroll
        for (int sb = 0; sb < 4; sb++)
#pragma unroll
            for (int r = 0; r < 4; r++) {
                float e = __expf(p[sb][r] - mnew);
                p[sb][r] = e;
                rsum += e;
            }
        rsum += __shfl_xor(rsum, 16, 64);
        rsum += __shfl_xor(rsum, 32, 64);
        lrun = lrun * alpha + rsum;
        mrun = mnew;
        float aC[4];
#pragma unroll
        for (int r = 0; r < 4; r++) aC[r] = __shfl(alpha, 4 * g + r, 64);
#pragma unroll
        for (int ni = 0; ni < 4; ni++)
#pragma unroll
            for (int r = 0; r < 4; r++) yacc[ni][r] *= aC[r];
#pragma unroll
        for (int sb = 0; sb < 4; sb++) {
            s16x4 pk;
#pragma unroll
            for (int r = 0; r < 4; r++) pk[r] = f2bf(p[sb][r]);
            int off = (r4 * 128 + (sb * 16 + 4 * g) * 2) ^ ((r4 & 7) << 4);
            *(s16x4*)((char*)&Ps[w][0] + off) = pk;
        }
#pragma unroll
        for (int kk = 0; kk < 2; kk++) {
            s16x8 pf = *(const s16x8*)((const char*)&Ps[w][0] +
                        ((r4 * 128 + kk * 64 + g * 16) ^ ((r4 & 7) << 4)));
#pragma unroll
            for (int ni = 0; ni < 4; ni++) {
                int vrow = ni * 16 + r4;
                s16x8 vb = *(const s16x8*)((const char*)&Vs[cur][0] +
                            ((vrow * 128 + kk * 64 + g * 16) ^ ((r4 & 7) << 4)));
                yacc[ni] = __builtin_amdgcn_mfma_f32_16x16x32_bf16(pf, vb, yacc[ni], 0, 0, 0);
            }
        }
        VMCNT0;
        __syncthreads();
    }
    float lC[4];
#pragma unroll
    for (int r = 0; r < 4; r++) lC[r] = __shfl(lrun, 4 * g + r, 64);
    int bb = bh >> 4, h = bh & 15;
#pragma unroll
    for (int ni = 0; ni < 4; ni++)
#pragma unroll
        for (int r = 0; r < 4; r++) {
            int q = qbase + w * 16 + 4 * g + r;
            y[((size_t)bb * T_SEQ + q) * C_DIM + h * HD + ni * 16 + r4] = yacc[ni][r] / lC[r];
        }
}

extern "C" void kernel_launch(void* const* d_in, const int* in_sizes, int n_in,
                              void* d_out, int out_size, void* d_ws, size_t ws_size,
                              hipStream_t stream) {
    (void)in_sizes; (void)n_in; (void)out_size; (void)ws_size;
    const float* x    = (const float*)d_in[0];
    const float* wq   = (const float*)d_in[1];
    const float* bq   = (const float*)d_in[2];
    const float* wk   = (const float*)d_in[3];
    const float* bk   = (const float*)d_in[4];
    const float* wvp  = (const float*)d_in[5];
    const float* bv   = (const float*)d_in[6];
    const float* ln1w = (const float*)d_in[7];
    const float* ln1b = (const float*)d_in[8];
    const float* ln2w = (const float*)d_in[9];
    const float* ln2b = (const float*)d_in[10];
    const float* wfc  = (const float*)d_in[11];
    const float* bfc  = (const float*)d_in[12];
    const float* wpr  = (const float*)d_in[13];
    const float* bpr  = (const float*)d_in[14];

    float* xout = (float*)d_out;                 // [2,2048,1024]
    float* kout = xout + 4194304;                // [2,16,2048,64] (vout = kout + 4194304)

    // workspace layout (~124 MB)
    short* wqkvt = (short*)d_ws;                 // [3072][1024] bf16
    short* wfct  = wqkvt + 3072 * 1024;          // [4096][1024]
    short* wprt  = wfct + 4096 * 1024;           // [1024][4096]
    short* hb    = wprt + 1024 * 4096;           // LN1 out bf16 [4096][1024]
    short* qb    = hb + 4096 * 1024;             // Q bf16 [B,H,T,D]
    short* kbuf  = qb + 4096 * 1024;             // K bf16 [B,H,T,D]
    short* vtb   = kbuf + 4096 * 1024;           // V bf16 transposed [B,H,D,T]
    short* h2b   = vtb + 4096 * 1024;            // LN2 out bf16
    short* fcb   = h2b + 4096 * 1024;            // gelu(fc) bf16 [4096][4096]
    float* ybuf  = (float*)(fcb + 4096 * 4096);  // attn out fp32 [4096][1024]

    dim3 tb(32, 8);
    transpose_cast_kernel<<<dim3(32, 32),  tb, 0, stream>>>(wq,  wqkvt,                1024, 1024);
    transpose_cast_kernel<<<dim3(32, 32),  tb, 0, stream>>>(wk,  wqkvt + 1024 * 1024,  1024, 1024);
    transpose_cast_kernel<<<dim3(32, 32),  tb, 0, stream>>>(wvp, wqkvt + 2048 * 1024,  1024, 1024);
    transpose_cast_kernel<<<dim3(128, 32), tb, 0, stream>>>(wfc, wfct,                 1024, 4096);
    transpose_cast_kernel<<<dim3(32, 128), tb, 0, stream>>>(wpr, wprt,                 4096, 1024);

    ln_kernel<<<4096, 256, 0, stream>>>(x, ln1w, ln1b, hb);

    // fused QKV GEMM: M=4096, N=3072, K=1024 — grid 16x12 = 192
    gemm3<0><<<dim3(16, 12), 512, 0, stream>>>(hb, wqkvt, 1024, 1024, 3072,
        bq, bk, bv, qb, kbuf, vtb, kout);

    attn_kernel<<<dim3(32, 32), 256, 0, stream>>>(qb, kbuf, vtb, ybuf);

    // x+y residual, LN2, and xout init (= x+y+b_proj)
    resln_kernel<<<4096, 256, 0, stream>>>(x, ybuf, ln2w, ln2b, bpr, h2b, xout);

    // MLP fc + gelu: M=4096, N=4096, K=1024 — grid 16x16 = 256
    gemm3<1><<<dim3(16, 16), 512, 0, stream>>>(h2b, wfct, 1024, 1024, 4096,
        bfc, nullptr, nullptr, fcb, nullptr, nullptr, nullptr);

    // MLP proj, split-K=4 (K-chunks of 1024), atomicAdd into xout — grid 16x16 = 256
    gemm3<2><<<dim3(16, 16), 512, 0, stream>>>(fcb, wprt, 1024, 4096, 1024,
        nullptr, nullptr, nullptr, nullptr, nullptr, nullptr, xout);
}

// Round 9
// 289.322 us; speedup vs baseline: 1.1536x; 1.1536x over previous
//
#include <hip/hip_runtime.h>
#include <hip/hip_bf16.h>

// Transformer block fwd: B=2, T=2048, C=1024, H=16, D=64.
// out = concat(x_out fp32 [2,2048,1024], k fp32 [2,16,2048,64], v fp32 [2,16,2048,64])

#define T_SEQ 2048
#define C_DIM 1024
#define HEADS 16
#define HD    64

typedef __attribute__((ext_vector_type(8))) short s16x8;   // 8 x bf16 (4 VGPR) — MFMA A/B frag
typedef __attribute__((ext_vector_type(4))) short s16x4;
typedef __attribute__((ext_vector_type(4))) float f32x4;   // MFMA C/D frag

__device__ __forceinline__ short f2bf(float f) {
    union { __hip_bfloat16 h; short s; } u;
    u.h = __float2bfloat16(f);
    return u.s;
}

// async global->LDS, 16B per lane. LDS dest = wave-uniform base + lane*16 (linear).
__device__ __forceinline__ void gload16(const void* g, void* l) {
    __builtin_amdgcn_global_load_lds(
        (const __attribute__((address_space(1))) void*)g,
        (__attribute__((address_space(3))) void*)l, 16, 0, 0);
}
#define VMCNT0 asm volatile("s_waitcnt vmcnt(0)" ::: "memory")

// ---------------- fused prep: 5 weight transposes (fp32 -> bf16, [K][N] -> [N][K]) + LN1 ----
// grid 1D, 256 threads. Blocks:
//  [0,3072)        wq/wk/wv -> wqkvt      (each 1024 blocks of 32x32 tile, K=N=1024)
//  [3072,7168)     wfc -> wfct            (4096 blocks, K=1024, N=4096)
//  [7168,11264)    wpr -> wprt            (4096 blocks, K=4096, N=1024)
//  [11264,15360)   LN1 rows               (4096 rows)
__global__ __launch_bounds__(256) void prep_kernel(
    const float* __restrict__ wq, const float* __restrict__ wk, const float* __restrict__ wv,
    const float* __restrict__ wfc, const float* __restrict__ wpr,
    short* __restrict__ wqkvt, short* __restrict__ wfct, short* __restrict__ wprt,
    const float* __restrict__ x, const float* __restrict__ ln1w, const float* __restrict__ ln1b,
    short* __restrict__ hb) {
    int b = blockIdx.x, tid = threadIdx.x;
    if (b < 11264) {
        // ---- transpose+cast path
        const float* W; short* Wt; int K, N, n0, k0;
        if (b < 3072) {
            int which = b >> 10, sub = b & 1023;
            W = (which == 0) ? wq : ((which == 1) ? wk : wv);
            Wt = wqkvt + which * 1024 * 1024;
            K = 1024; N = 1024;
            n0 = (sub & 31) * 32; k0 = (sub >> 5) * 32;
        } else if (b < 7168) {
            int sub = b - 3072;
            W = wfc; Wt = wfct; K = 1024; N = 4096;
            n0 = (sub & 127) * 32; k0 = (sub >> 7) * 32;
        } else {
            int sub = b - 7168;
            W = wpr; Wt = wprt; K = 4096; N = 1024;
            n0 = (sub & 31) * 32; k0 = (sub >> 5) * 32;
        }
        __shared__ float t[32][33];
        int ty = tid >> 3, tx = tid & 7;           // load: row ty, float4 col tx
        float4 v = *(const float4*)&W[(size_t)(k0 + ty) * N + n0 + tx * 4];
        t[ty][tx * 4 + 0] = v.x; t[ty][tx * 4 + 1] = v.y;
        t[ty][tx * 4 + 2] = v.z; t[ty][tx * 4 + 3] = v.w;
        __syncthreads();
        int r = tid >> 3, c = tid & 7;             // store: n-row r, k-chunk c (4 shorts)
        s16x4 o;
#pragma unroll
        for (int j = 0; j < 4; j++) o[j] = f2bf(t[c * 4 + j][r]);
        *(s16x4*)&Wt[(size_t)(n0 + r) * K + k0 + c * 4] = o;
    } else {
        // ---- LN1 path
        int row = b - 11264;
        float4 v = ((const float4*)(x + (size_t)row * C_DIM))[tid];
        float s  = v.x + v.y + v.z + v.w;
        float sq = v.x * v.x + v.y * v.y + v.z * v.z + v.w * v.w;
#pragma unroll
        for (int off = 32; off > 0; off >>= 1) {
            s  += __shfl_down(s, off, 64);
            sq += __shfl_down(sq, off, 64);
        }
        __shared__ float rs[4], rq[4];
        int wv2 = tid >> 6, ln = tid & 63;
        if (ln == 0) { rs[wv2] = s; rq[wv2] = sq; }
        __syncthreads();
        s = rs[0] + rs[1] + rs[2] + rs[3];
        sq = rq[0] + rq[1] + rq[2] + rq[3];
        float mean = s * (1.f / C_DIM);
        float rstd = rsqrtf(sq * (1.f / C_DIM) - mean * mean + 1e-5f);
        float4 wv4 = ((const float4*)ln1w)[tid];
        float4 bv4 = ((const float4*)ln1b)[tid];
        s16x4 o;
        o[0] = f2bf((v.x - mean) * rstd * wv4.x + bv4.x);
        o[1] = f2bf((v.y - mean) * rstd * wv4.y + bv4.y);
        o[2] = f2bf((v.z - mean) * rstd * wv4.z + bv4.z);
        o[3] = f2bf((v.w - mean) * rstd * wv4.w + bv4.w);
        *(s16x4*)(hb + (size_t)row * C_DIM + tid * 4) = o;
    }
}

// ---- residual + LN2 + PROJ-output init: xout = x+y+b_proj (fp32), h2 = LN(x+y) bf16 ----
__global__ __launch_bounds__(256) void resln_kernel(
    const float* __restrict__ x, const float* __restrict__ y,
    const float* __restrict__ w, const float* __restrict__ b,
    const float* __restrict__ bproj,
    short* __restrict__ out, float* __restrict__ xout) {
    int row = blockIdx.x, tid = threadIdx.x;
    float4 vx = ((const float4*)(x + row * C_DIM))[tid];
    float4 vy = ((const float4*)(y + row * C_DIM))[tid];
    float4 v;
    v.x = vx.x + vy.x; v.y = vx.y + vy.y; v.z = vx.z + vy.z; v.w = vx.w + vy.w;
    float4 bp = ((const float4*)bproj)[tid];
    float4 xo;
    xo.x = v.x + bp.x; xo.y = v.y + bp.y; xo.z = v.z + bp.z; xo.w = v.w + bp.w;
    ((float4*)(xout + row * C_DIM))[tid] = xo;   // PROJ GEMM atomically adds onto this
    float s  = v.x + v.y + v.z + v.w;
    float sq = v.x * v.x + v.y * v.y + v.z * v.z + v.w * v.w;
#pragma unroll
    for (int off = 32; off > 0; off >>= 1) {
        s  += __shfl_down(s, off, 64);
        sq += __shfl_down(sq, off, 64);
    }
    __shared__ float rs[4], rq[4];
    int wv = tid >> 6, ln = tid & 63;
    if (ln == 0) { rs[wv] = s; rq[wv] = sq; }
    __syncthreads();
    s = rs[0] + rs[1] + rs[2] + rs[3];
    sq = rq[0] + rq[1] + rq[2] + rq[3];
    float mean = s * (1.f / C_DIM);
    float rstd = rsqrtf(sq * (1.f / C_DIM) - mean * mean + 1e-5f);
    float4 wv4 = ((const float4*)w)[tid];
    float4 bv4 = ((const float4*)b)[tid];
    s16x4 o;
    o[0] = f2bf((v.x - mean) * rstd * wv4.x + bv4.x);
    o[1] = f2bf((v.y - mean) * rstd * wv4.y + bv4.y);
    o[2] = f2bf((v.z - mean) * rstd * wv4.z + bv4.z);
    o[3] = f2bf((v.w - mean) * rstd * wv4.w + bv4.w);
    *(s16x4*)(out + row * C_DIM + tid * 4) = o;
}

// ---------------- m97-replica GEMM: 128x128, 4 waves, single 32KB LDS, FORCED 3 waves/SIMD ----
// C = A[M,Kc](bf16, stride LDA) @ Bt[N,Kc]^T + epilogue. BK=64, wave tile 64x64 (acc 64 VGPR).
// __launch_bounds__(256,3): caps VGPR so 12 waves/CU = 3 BLOCKS co-resident — inter-block wave
// overlap (m114) hides the per-block stage+vmcnt0+barrier drain (m97's 874 TF mechanism).
// Loop (R2-proven correct): stage(0); drain; barrier; { compute(t); barrier; stage(t+1); drain;
// barrier }. Pre-swizzled gload source chunk (lc^lr), linear LDS dest, XOR (row&7)<<4 reads.
// MODE 0: fused QKV; MODE 1: FC+GELU; MODE 2: split-K partial, atomicAdd into of0 (no bias).
template<int MODE>
__global__ __launch_bounds__(256, 3) void gemm97(
    const short* __restrict__ A, const short* __restrict__ Bt,
    int K, int LDA, int N,
    const float* __restrict__ b0, const float* __restrict__ b1, const float* __restrict__ b2,
    short* __restrict__ os0, short* __restrict__ os1, short* __restrict__ os2,
    float* __restrict__ of0) {
    __shared__ short As[128 * 64];
    __shared__ short Bs[128 * 64];
    const int tid = threadIdx.x;
    const int wv = tid >> 6, lane = tid & 63, g = lane >> 4, r4 = lane & 15;
    const int wr = wv >> 1, wc = wv & 1;
    const int lr = lane >> 3, lc = lane & 7, sc = lc ^ lr;

    const int nwg = gridDim.x * gridDim.y;
    const int bid = blockIdx.y * gridDim.x + blockIdx.x;
    const int swz = (bid & 7) * (nwg >> 3) + (bid >> 3);   // bijective, nwg % 8 == 0
    const int m0 = (swz % gridDim.x) * 128;
    const int yy = swz / gridDim.x;
    int n0, kch;
    if constexpr (MODE == 2) {
        kch = yy >> 3;            // 4 K-chunks
        n0 = (yy & 7) * 128;      // N/128 = 8
    } else {
        kch = 0;
        n0 = yy * 128;
    }
    const size_t kbase = (size_t)kch * K;
    const size_t aoff = (size_t)m0 * LDA + kbase + sc * 8;
    const size_t boff = (size_t)n0 * LDA + kbase + sc * 8;

    const f32x4 zero4 = {0.f, 0.f, 0.f, 0.f};
    f32x4 acc[4][4];
#pragma unroll
    for (int i = 0; i < 4; i++)
#pragma unroll
        for (int j = 0; j < 4; j++) acc[i][j] = zero4;

    auto stage = [&](int t1) {
#pragma unroll
        for (int j = 0; j < 4; j++) {
            int rg = wv * 4 + j;                   // 16 groups x 8 rows = 128
            gload16(A  + aoff + (size_t)(rg * 8 + lr) * LDA + (size_t)t1 * 64, &As[rg * 512]);
            gload16(Bt + boff + (size_t)(rg * 8 + lr) * LDA + (size_t)t1 * 64, &Bs[rg * 512]);
        }
    };

    stage(0);
    VMCNT0;
    __syncthreads();

    const int NT = K >> 6;
    for (int t = 0; t < NT; ++t) {
#pragma unroll
        for (int kk = 0; kk < 2; kk++) {
            s16x8 af[4], bfr[4];
#pragma unroll
            for (int mf = 0; mf < 4; mf++) {
                int row = wr * 64 + mf * 16 + r4;
                af[mf] = *(const s16x8*)((const char*)As +
                          ((row * 128 + kk * 64 + g * 16) ^ ((row & 7) << 4)));
            }
#pragma unroll
            for (int nf = 0; nf < 4; nf++) {
                int row = wc * 64 + nf * 16 + r4;
                bfr[nf] = *(const s16x8*)((const char*)Bs +
                           ((row * 128 + kk * 64 + g * 16) ^ ((row & 7) << 4)));
            }
#pragma unroll
            for (int mf = 0; mf < 4; mf++)
#pragma unroll
                for (int nf = 0; nf < 4; nf++)
                    acc[mf][nf] = __builtin_amdgcn_mfma_f32_16x16x32_bf16(
                        af[mf], bfr[nf], acc[mf][nf], 0, 0, 0);
        }
        __syncthreads();          // all waves done reading tile t
        if (t + 1 < NT) stage(t + 1);
        VMCNT0;
        __syncthreads();          // tile t+1 visible
    }

    // epilogue: D layout col = lane&15, row = 4*(lane>>4)+r  [verified m89/m91]
#pragma unroll
    for (int mf = 0; mf < 4; mf++) {
#pragma unroll
        for (int nf = 0; nf < 4; nf++) {
            int n = n0 + wc * 64 + nf * 16 + r4;
#pragma unroll
            for (int r = 0; r < 4; r++) {
                int m = m0 + wr * 64 + mf * 16 + 4 * g + r;
                float val = acc[mf][nf][r];
                if constexpr (MODE == 0) {
                    int sel = n >> 10, nn = n & 1023;
                    const float* bp = (sel == 0) ? b0 : ((sel == 1) ? b1 : b2);
                    val += bp[nn];
                    int bb2 = m >> 11, tt = m & 2047, h = nn >> 6, d = nn & 63;
                    int qi = ((bb2 * HEADS + h) * T_SEQ + tt) * HD + d;
                    if (sel == 0) {
                        os0[qi] = f2bf(val);
                    } else if (sel == 1) {
                        os1[qi] = f2bf(val);
                        of0[qi] = val;                   // kout
                    } else {
                        of0[4194304 + qi] = val;        // vout
                        os2[((bb2 * HEADS + h) * HD + d) * T_SEQ + tt] = f2bf(val);
                    }
                } else if constexpr (MODE == 1) {
                    val += b0[n];
                    val = 0.5f * val * (1.f + erff(val * 0.70710678118f));  // exact GELU
                    os0[m * N + n] = f2bf(val);
                } else {
                    atomicAdd(&of0[(size_t)m * N + n], val);  // onto x+y+b_proj init
                }
            }
        }
    }
}

// ---------------- causal flash attention (swapped QK^T, lane-local softmax) ----------------
__global__ __launch_bounds__(256) void attn_kernel(
    const short* __restrict__ qb, const short* __restrict__ kb,
    const short* __restrict__ vtb, float* __restrict__ y) {
    __shared__ short Ks[2][64 * 64];
    __shared__ short Vs[2][64 * 64];
    __shared__ short Ps[4][16 * 64];
    int qtr = (gridDim.x - 1) - blockIdx.x;
    int bh = blockIdx.y;
    int tid = threadIdx.x, w = tid >> 6, lane = tid & 63, g = lane >> 4, r4 = lane & 15;
    int qbase = qtr * 64;
    int lr = lane >> 3, lc = lane & 7, sc = lc ^ lr;

    const short* Qp = qb + ((size_t)bh * T_SEQ + qbase + w * 16 + r4) * HD;
    s16x8 qf0 = *(const s16x8*)&Qp[g * 8];
    s16x8 qf1 = *(const s16x8*)&Qp[32 + g * 8];

    const f32x4 zero4 = {0.f, 0.f, 0.f, 0.f};
    f32x4 yacc[4];
#pragma unroll
    for (int ni = 0; ni < 4; ni++) yacc[ni] = zero4;
    float mrun = -1e30f, lrun = 0.f;

#pragma unroll
    for (int j = 0; j < 2; j++) {
        int rw = (w * 2 + j) * 8 + lr;
        gload16(kb  + ((size_t)bh * T_SEQ + rw) * HD + sc * 8, &Ks[0][(w * 2 + j) * 512]);
        gload16(vtb + ((size_t)bh * HD + rw) * T_SEQ + sc * 8, &Vs[0][(w * 2 + j) * 512]);
    }
    VMCNT0;
    __syncthreads();

    int nst = qtr + 1;
    for (int st = 0; st < nst; ++st) {
        int cur = st & 1;
        int s0 = st * 64;
        if (st + 1 < nst) {
#pragma unroll
            for (int j = 0; j < 2; j++) {
                int rw = (w * 2 + j) * 8 + lr;
                gload16(kb  + ((size_t)bh * T_SEQ + s0 + 64 + rw) * HD + sc * 8,
                        &Ks[cur ^ 1][(w * 2 + j) * 512]);
                gload16(vtb + ((size_t)bh * HD + rw) * T_SEQ + s0 + 64 + sc * 8,
                        &Vs[cur ^ 1][(w * 2 + j) * 512]);
            }
        }
        f32x4 sacc[4];
#pragma unroll
        for (int sb = 0; sb < 4; sb++) sacc[sb] = zero4;
#pragma unroll
        for (int kk = 0; kk < 2; kk++) {
            s16x8 qf = (kk == 0) ? qf0 : qf1;
#pragma unroll
            for (int sb = 0; sb < 4; sb++) {
                int srow = sb * 16 + r4;
                s16x8 kf = *(const s16x8*)((const char*)&Ks[cur][0] +
                            ((srow * 128 + kk * 64 + g * 16) ^ ((r4 & 7) << 4)));
                sacc[sb] = __builtin_amdgcn_mfma_f32_16x16x32_bf16(kf, qf, sacc[sb], 0, 0, 0);
            }
        }
        bool diag = (st == qtr);
        float p[4][4];
        float mx = -1e30f;
#pragma unroll
        for (int sb = 0; sb < 4; sb++)
#pragma unroll
            for (int r = 0; r < 4; r++) {
                float v = sacc[sb][r] * 0.125f;
                if (diag) {
                    int kv = s0 + sb * 16 + 4 * g + r;
                    int qg = qbase + w * 16 + r4;
                    if (kv > qg) v = -1e30f;
                }
                p[sb][r] = v;
                mx = fmaxf(mx, v);
            }
        mx = fmaxf(mx, __shfl_xor(mx, 16, 64));
        mx = fmaxf(mx, __shfl_xor(mx, 32, 64));
        float mnew = fmaxf(mrun, mx);
        float alpha = __expf(mrun - mnew);
        float rsum = 0.f;
#pragma unroll
        for (int sb = 0; sb < 4; sb++)
#pragma unroll
            for (int r = 0; r < 4; r++) {
                float e = __expf(p[sb][r] - mnew);
                p[sb][r] = e;
                rsum += e;
            }
        rsum += __shfl_xor(rsum, 16, 64);
        rsum += __shfl_xor(rsum, 32, 64);
        lrun = lrun * alpha + rsum;
        mrun = mnew;
        float aC[4];
#pragma unroll
        for (int r = 0; r < 4; r++) aC[r] = __shfl(alpha, 4 * g + r, 64);
#pragma unroll
        for (int ni = 0; ni < 4; ni++)
#pragma unroll
            for (int r = 0; r < 4; r++) yacc[ni][r] *= aC[r];
#pragma unroll
        for (int sb = 0; sb < 4; sb++) {
            s16x4 pk;
#pragma unroll
            for (int r = 0; r < 4; r++) pk[r] = f2bf(p[sb][r]);
            int off = (r4 * 128 + (sb * 16 + 4 * g) * 2) ^ ((r4 & 7) << 4);
            *(s16x4*)((char*)&Ps[w][0] + off) = pk;
        }
#pragma unroll
        for (int kk = 0; kk < 2; kk++) {
            s16x8 pf = *(const s16x8*)((const char*)&Ps[w][0] +
                        ((r4 * 128 + kk * 64 + g * 16) ^ ((r4 & 7) << 4)));
#pragma unroll
            for (int ni = 0; ni < 4; ni++) {
                int vrow = ni * 16 + r4;
                s16x8 vb = *(const s16x8*)((const char*)&Vs[cur][0] +
                            ((vrow * 128 + kk * 64 + g * 16) ^ ((r4 & 7) << 4)));
                yacc[ni] = __builtin_amdgcn_mfma_f32_16x16x32_bf16(pf, vb, yacc[ni], 0, 0, 0);
            }
        }
        VMCNT0;
        __syncthreads();
    }
    float lC[4];
#pragma unroll
    for (int r = 0; r < 4; r++) lC[r] = __shfl(lrun, 4 * g + r, 64);
    int bb = bh >> 4, h = bh & 15;
#pragma unroll
    for (int ni = 0; ni < 4; ni++)
#pragma unroll
        for (int r = 0; r < 4; r++) {
            int q = qbase + w * 16 + 4 * g + r;
            y[((size_t)bb * T_SEQ + q) * C_DIM + h * HD + ni * 16 + r4] = yacc[ni][r] / lC[r];
        }
}

extern "C" void kernel_launch(void* const* d_in, const int* in_sizes, int n_in,
                              void* d_out, int out_size, void* d_ws, size_t ws_size,
                              hipStream_t stream) {
    (void)in_sizes; (void)n_in; (void)out_size; (void)ws_size;
    const float* x    = (const float*)d_in[0];
    const float* wq   = (const float*)d_in[1];
    const float* bq   = (const float*)d_in[2];
    const float* wk   = (const float*)d_in[3];
    const float* bk   = (const float*)d_in[4];
    const float* wvp  = (const float*)d_in[5];
    const float* bv   = (const float*)d_in[6];
    const float* ln1w = (const float*)d_in[7];
    const float* ln1b = (const float*)d_in[8];
    const float* ln2w = (const float*)d_in[9];
    const float* ln2b = (const float*)d_in[10];
    const float* wfc  = (const float*)d_in[11];
    const float* bfc  = (const float*)d_in[12];
    const float* wpr  = (const float*)d_in[13];
    const float* bpr  = (const float*)d_in[14];

    float* xout = (float*)d_out;                 // [2,2048,1024]
    float* kout = xout + 4194304;                // [2,16,2048,64] (vout = kout + 4194304)

    // workspace layout (~124 MB)
    short* wqkvt = (short*)d_ws;                 // [3072][1024] bf16
    short* wfct  = wqkvt + 3072 * 1024;          // [4096][1024]
    short* wprt  = wfct + 4096 * 1024;           // [1024][4096]
    short* hb    = wprt + 1024 * 4096;           // LN1 out bf16 [4096][1024]
    short* qb    = hb + 4096 * 1024;             // Q bf16 [B,H,T,D]
    short* kbuf  = qb + 4096 * 1024;             // K bf16 [B,H,T,D]
    short* vtb   = kbuf + 4096 * 1024;           // V bf16 transposed [B,H,D,T]
    short* h2b   = vtb + 4096 * 1024;            // LN2 out bf16
    short* fcb   = h2b + 4096 * 1024;            // gelu(fc) bf16 [4096][4096]
    float* ybuf  = (float*)(fcb + 4096 * 4096);  // attn out fp32 [4096][1024]

    // fused transposes + LN1
    prep_kernel<<<15360, 256, 0, stream>>>(wq, wk, wvp, wfc, wpr,
        wqkvt, wfct, wprt, x, ln1w, ln1b, hb);

    // fused QKV GEMM: M=4096, N=3072, K=1024 — grid 32x24 = 768 (3 blocks/CU)
    gemm97<0><<<dim3(32, 24), 256, 0, stream>>>(hb, wqkvt, 1024, 1024, 3072,
        bq, bk, bv, qb, kbuf, vtb, kout);

    attn_kernel<<<dim3(32, 32), 256, 0, stream>>>(qb, kbuf, vtb, ybuf);

    // x+y residual, LN2, and xout init (= x+y+b_proj)
    resln_kernel<<<4096, 256, 0, stream>>>(x, ybuf, ln2w, ln2b, bpr, h2b, xout);

    // MLP fc + gelu: M=4096, N=4096, K=1024 — grid 32x32 = 1024 (4 blocks/CU avail)
    gemm97<1><<<dim3(32, 32), 256, 0, stream>>>(h2b, wfct, 1024, 1024, 4096,
        bfc, nullptr, nullptr, fcb, nullptr, nullptr, nullptr);

    // MLP proj, split-K=4 (K-chunks of 1024), atomicAdd into xout — grid 32x32 = 1024
    gemm97<2><<<dim3(32, 32), 256, 0, stream>>>(fcb, wprt, 1024, 4096, 1024,
        nullptr, nullptr, nullptr, nullptr, nullptr, nullptr, xout);
}